// Round 2
// 191.606 us; speedup vs baseline: 1.0047x; 1.0047x over previous
//
#include <hip/hip_runtime.h>
#include <math.h>

#define Bv 32
#define Cv 256
#define Hv 32
#define Wv 32
#define Pv 1024                  // H*W
#define TSTRIDE (Bv * Cv * Pv)   // elements between T-slabs = 8388608
#define NCH 16                   // channel chunks
#define CC  16                   // channels per chunk
#define PSPLIT 4                 // pixel quarters per (chunk,b)

// ---------------------------------------------------------------------------
// Phase 1 (R4-proven load pattern, absmax 0.0, ~87% of achievable HBM BW):
// grid (NCH*PSPLIT, B) = 2048 blocks (8/CU, 32 waves/CU), 256 threads.
// Block: 16 channels x 256 pixels x 4 T. cl = tid>>6 picks a channel sub-row,
// lane picks a float4 -> each wave reads contiguous 1 KiB; 16 unrolled loads
// per thread keep a deep vmcnt pipeline. LDS combine across the 4 sub-rows.
// No fences, no atomics (R3 showed device-scope arrival costs ~50 us).
// R5 change: partials now stored [b][chunk][p] (was [chunk][b][p]) so that
// phase 2 reads one contiguous 128 KB run per block. Store coalescing here is
// identical (same 1 KiB vector stores, different base offset).
// ---------------------------------------------------------------------------
__global__ __launch_bounds__(256) void lss_phase1(
    const float* __restrict__ x,
    float* __restrict__ part1,
    float* __restrict__ part2)
{
    const int chunk = blockIdx.x >> 2;       // 0..15
    const int ps    = blockIdx.x & 3;        // 0..3 pixel quarter
    const int b     = blockIdx.y;
    const int tid   = threadIdx.x;
    const int cl    = tid >> 6;              // 0..3 channel sub-row
    const int lane  = tid & 63;
    const int p0    = ps * 256 + (lane << 2);

    float s1x = 0.f, s1y = 0.f, s1z = 0.f, s1w = 0.f;
    float s2x = 0.f, s2y = 0.f, s2z = 0.f, s2w = 0.f;

    const float* bp = x + ((size_t)b * Cv + chunk * CC + cl) * Pv + p0;

    #pragma unroll
    for (int g = 0; g < CC / 4; ++g) {       // c = chunk*16 + cl + 4*g
        const float4 v0 = *(const float4*)(bp);
        const float4 v1 = *(const float4*)(bp + (size_t)TSTRIDE);
        const float4 v2 = *(const float4*)(bp + (size_t)2 * TSTRIDE);
        const float4 v3 = *(const float4*)(bp + (size_t)3 * TSTRIDE);
        bp += 4 * Pv;

        const float mx = (v0.x + v1.x + v2.x + v3.x) * 0.25f;
        const float my = (v0.y + v1.y + v2.y + v3.y) * 0.25f;
        const float mz = (v0.z + v1.z + v2.z + v3.z) * 0.25f;
        const float mw = (v0.w + v1.w + v2.w + v3.w) * 0.25f;

        s1x += mx;  s2x += mx * mx;
        s1y += my;  s2y += my * my;
        s1z += mz;  s2z += mz * mz;
        s1w += mw;  s2w += mw * mw;
    }

    __shared__ float4 l1[4][64];
    __shared__ float4 l2[4][64];
    l1[cl][lane].x = s1x; l1[cl][lane].y = s1y; l1[cl][lane].z = s1z; l1[cl][lane].w = s1w;
    l2[cl][lane].x = s2x; l2[cl][lane].y = s2y; l2[cl][lane].z = s2z; l2[cl][lane].w = s2w;
    __syncthreads();

    if (tid < 128) {
        const int t = tid & 63;
        const float4* src = (tid < 64) ? &l1[0][0] : &l2[0][0];
        const float4 a = src[t], c = src[64 + t], d = src[128 + t], e = src[192 + t];
        float4 r;
        r.x = (a.x + c.x) + (d.x + e.x);
        r.y = (a.y + c.y) + (d.y + e.y);
        r.z = (a.z + c.z) + (d.z + e.z);
        r.w = (a.w + c.w) + (d.w + e.w);
        float* dst = (tid < 64) ? part1 : part2;
        // [b][chunk][p] layout
        *(float4*)(dst + ((size_t)b * NCH + chunk) * Pv + ps * 256 + (t << 2)) = r;
    }
}

// ---------------------------------------------------------------------------
// Phase 2 (R5 rewrite): one block per batch, 256 threads, 4 pixels/thread.
// All global traffic is float4/int4 (1 KiB per wave-instruction); each block
// reads ONE contiguous 128 KB run of partials ([b][chunk][p] layout, L2-hot).
// 4 waves instead of 16: cheaper barriers, 4-entry LDS combine for softmax.
// 3x3 zero-padded box sum via haloed LDS tile as before.
// ---------------------------------------------------------------------------
__global__ __launch_bounds__(256) void lss_final(
    const float* __restrict__ part1,
    const float* __restrict__ part2,
    const int*   __restrict__ mask,
    float*       __restrict__ out)
{
    const int b   = blockIdx.x;
    const int tid = threadIdx.x;           // 0..255, 4 consecutive pixels each
    const int yy  = tid >> 3;              // row 0..31
    const int x0  = (tid & 7) << 2;        // col 0,4,...,28
    const int wid = tid >> 6;              // 4 waves

    __shared__ float cs[(Hv + 2) * (Wv + 2)];   // 34*34 haloed tile
    __shared__ float wred[4];

    // contiguous chunk reduction: 16 x float4 (part1) + 16 x float4 (part2)
    const float4* p1 = (const float4*)(part1 + (size_t)b * NCH * Pv) + tid;
    const float4* p2 = (const float4*)(part2 + (size_t)b * NCH * Pv) + tid;

    float4 s1 = make_float4(0.f, 0.f, 0.f, 0.f);
    float4 s2 = make_float4(0.f, 0.f, 0.f, 0.f);
    #pragma unroll
    for (int ch = 0; ch < NCH; ++ch) {
        const float4 a = p1[(size_t)ch * (Pv / 4)];
        const float4 c = p2[(size_t)ch * (Pv / 4)];
        s1.x += a.x; s1.y += a.y; s1.z += a.z; s1.w += a.w;
        s2.x += c.x; s2.y += c.y; s2.z += c.z; s2.w += c.w;
    }

    const float csv[4] = { s1.x, s1.y, s1.z, s1.w };
    const float nxv[4] = { sqrtf(s2.x), sqrtf(s2.y), sqrtf(s2.z), sqrtf(s2.w) };

    // zero halo tile, then place interior channel-sums
    for (int i = tid; i < (Hv + 2) * (Wv + 2); i += 256) cs[i] = 0.f;
    __syncthreads();
    {
        float* row = &cs[(yy + 1) * (Wv + 2) + x0 + 1];
        row[0] = csv[0]; row[1] = csv[1]; row[2] = csv[2]; row[3] = csv[3];
    }
    __syncthreads();

    // 3x3 box sums for the 4 pixels
    float lm[4];
    #pragma unroll
    for (int i = 0; i < 4; ++i) {
        float acc = 0.f;
        #pragma unroll
        for (int dy = 0; dy < 3; ++dy) {
            const float* r = &cs[(yy + dy) * (Wv + 2) + x0 + i];
            acc += r[0] + r[1] + r[2];
        }
        lm[i] = acc * (1.0f / 9.0f);
    }

    // cosine sim + mask -> scores
    const int4 mk = *(const int4*)(mask + (size_t)b * Pv + (tid << 2));
    const int mki[4] = { mk.x, mk.y, mk.z, mk.w };
    float sc[4];
    #pragma unroll
    for (int i = 0; i < 4; ++i) {
        const float ny  = 16.0f * fabsf(lm[i]);   // sqrt(256)*|lm|
        const float sim = (lm[i] * csv[i]) / (fmaxf(nxv[i], 1e-6f) * fmaxf(ny, 1e-6f));
        sc[i] = mki[i] ? -INFINITY : -sim;
    }

    // max reduce: 4 local + wave shuffle + 4-entry LDS combine
    float v = fmaxf(fmaxf(sc[0], sc[1]), fmaxf(sc[2], sc[3]));
    #pragma unroll
    for (int off = 32; off > 0; off >>= 1)
        v = fmaxf(v, __shfl_xor(v, off, 64));
    if ((tid & 63) == 0) wred[wid] = v;
    __syncthreads();
    const float m = fmaxf(fmaxf(wred[0], wred[1]), fmaxf(wred[2], wred[3]));
    __syncthreads();

    float e[4];
    #pragma unroll
    for (int i = 0; i < 4; ++i) e[i] = expf(sc[i] - m);   // masked lanes -> 0

    // sum reduce
    v = (e[0] + e[1]) + (e[2] + e[3]);
    #pragma unroll
    for (int off = 32; off > 0; off >>= 1)
        v += __shfl_xor(v, off, 64);
    if ((tid & 63) == 0) wred[wid] = v;
    __syncthreads();
    const float inv = 1.0f / ((wred[0] + wred[1]) + (wred[2] + wred[3]));

    float4 o;
    o.x = e[0] * inv; o.y = e[1] * inv; o.z = e[2] * inv; o.w = e[3] * inv;
    *(float4*)(out + (size_t)b * Pv + (tid << 2)) = o;
}

extern "C" void kernel_launch(void* const* d_in, const int* in_sizes, int n_in,
                              void* d_out, int out_size, void* d_ws, size_t ws_size,
                              hipStream_t stream) {
    const float* x    = (const float*)d_in[0];
    const int*   mask = (const int*)d_in[1];
    float*       out  = (float*)d_out;

    float* part1 = (float*)d_ws;                      // B*NCH*P floats = 2 MB
    float* part2 = part1 + (size_t)NCH * Bv * Pv;     // 2 MB

    dim3 g1(NCH * PSPLIT, Bv);
    lss_phase1<<<g1, 256, 0, stream>>>(x, part1, part2);
    lss_final<<<Bv, 256, 0, stream>>>(part1, part2, mask, out);
}